// Round 18
// baseline (41.092 us; speedup 1.0000x reference)
//
#include <hip/hip_runtime.h>
#include <stdint.h>

// Shapes fixed by setup_inputs: B=4, D=20, H=W=128, HW=16384, 1024 tiles of 64 voxels.
// R18 = R17 body (17.8us, = R15's 17.7) with the fin kernel MERGED via
// spin-wait finalize (eliminates 2nd launch + inter-kernel gap ~3-4us):
//  - each block signals on one of 16 counters spaced 64B apart (blockIdx&15 ->
//    exactly 64 increments/counter; no same-line pileup -- the R2-R6 lesson).
//  - block 0 wave 0, after its own tile, spins until all 16 counters hit 64,
//    __threadfence-acquires, reduces the 1024 records, writes out[0].
//    Deadlock-safe: spinning block occupies one slot; all others retire
//    independently (forward progress regardless of residency).
//  - counters live at ws float-offset 8192 (byte 32768..33791); records use
//    ws[0..8191] -- d_ws is far larger (harness poisons ~268MB).
#define HW     16384
#define NTILES 1024
#define NCTR   16
#define INFI   0x7f800000

__global__ __launch_bounds__(512, 8) void chamfer_all(
    const float* __restrict__ pred,   // [B, 60, HW]  channel c*20+i
    const float* __restrict__ gt,     // [B, 60, HW]  channel j*3+c
    const float* __restrict__ cmask,  // [B, 20, HW]
    const float* __restrict__ vmask,  // [B, HW]
    const float* __restrict__ pnum,   // [B, HW]
    const float* __restrict__ gnum,   // [B, HW]
    float* __restrict__ ws,
    float* __restrict__ out)
{
    __shared__ int rm_m[20][64];   // per-row selected min (float bits)
    __shared__ int cd_s[20][64];   // per-col min (d2s)
    __shared__ int mx_s[64];       // per-voxel max dist
    __shared__ int bt_s[64];       // per-voxel cmask bits

    const int tid  = threadIdx.x;
    const int lane = tid & 63;     // voxel within tile
    const int w    = tid >> 6;     // wave 0..7
    const int ri   = w >> 2;       // 0..1 -> rows i0..i0+9
    const int cj   = w & 3;        // 0..3 -> cols j0..j0+4
    const int i0   = ri * 10, j0 = cj * 5;
    const int k    = blockIdx.x * 64 + lane;
    const int b    = k >> 14;
    const int hw   = k & (HW - 1);
    const size_t pb = (size_t)b * 60 * HW + hw;
    const size_t cb = (size_t)b * 20 * HW + hw;

    // ---- independent coalesced loads up-front (256B per wave-instr)
    float dxv[5], dyv[5], dzv[5], cmf[5];
    #pragma unroll
    for (int jj = 0; jj < 5; ++jj) {
        dxv[jj] = gt[pb + (size_t)(3 * (j0 + jj)    ) * HW];
        dyv[jj] = gt[pb + (size_t)(3 * (j0 + jj) + 1) * HW];
        dzv[jj] = gt[pb + (size_t)(3 * (j0 + jj) + 2) * HW];
        cmf[jj] = cmask[cb + (size_t)(j0 + jj) * HW];
    }
    float vw = 0.f, pn = 0.f, gn = 0.f;
    if (w == 0) { vw = vmask[k]; pn = pnum[k]; gn = gnum[k]; }

    // ---- init LDS while loads are in flight
    {
        int* pm = &rm_m[0][0]; int* pc = &cd_s[0][0];
        #pragma unroll
        for (int q = 0; q < 3; ++q) {
            const int t = tid + q * 512;
            if (t < 1280) { pm[t] = INFI; pc[t] = INFI; }
        }
        if (tid < 64) { mx_s[tid] = 0; bt_s[tid] = 0; }
    }
    __syncthreads();

    // ---- publish cmask bits BEFORE the hot loop (ri==0 waves cover all cols)
    unsigned mybits = 0u;
    #pragma unroll
    for (int jj = 0; jj < 5; ++jj)
        if (cmf[jj] > 0.f) mybits |= 1u << jj;
    if (ri == 0 && mybits) atomicOr(&bt_s[lane], (int)(mybits << j0));
    __syncthreads();

    const unsigned cmbits = (unsigned)bt_s[lane];
    // selected cols for the s2d row-min: masked cols if any masked globally,
    // else all cols (their min + maxd is exact via vals[1])
    const unsigned sel = cmbits ? mybits : 0x1Fu;

    const float INF = __int_as_float(INFI);
    float rmm[10], cds[5], mx = 0.f;
    #pragma unroll
    for (int t = 0; t < 10; ++t) rmm[t] = INF;
    #pragma unroll
    for (int t = 0; t < 5; ++t) cds[t] = INF;

    #pragma unroll
    for (int r = 0; r < 10; ++r) {
        const int i = i0 + r;
        const float sx = pred[pb + (size_t)(i)      * HW];
        const float sy = pred[pb + (size_t)(20 + i) * HW];
        const float sz = pred[pb + (size_t)(40 + i) * HW];
        #pragma unroll
        for (int jj = 0; jj < 5; ++jj) {
            float d = fabsf(sx - dxv[jj]) + fabsf(sy - dyv[jj]) + fabsf(sz - dzv[jj]);
            mx      = fmaxf(mx, d);
            cds[jj] = fminf(cds[jj], d);
            rmm[r]  = fminf(rmm[r], ((sel >> jj) & 1u) ? d : INF);
        }
    }

    // ---- cross-wave combine: int atomics (all values >= 0 -> int order == float order)
    #pragma unroll
    for (int r = 0; r < 10; ++r)
        atomicMin(&rm_m[i0 + r][lane], __float_as_int(rmm[r]));
    #pragma unroll
    for (int jj = 0; jj < 5; ++jj)
        atomicMin(&cd_s[j0 + jj][lane], __float_as_int(cds[jj]));
    atomicMax(&mx_s[lane], __float_as_int(mx));
    __syncthreads();

    // ---- per-tile finalize: wave 0, lane = voxel
    if (w == 0) {
        float srcA = 0.f;
        #pragma unroll
        for (int i = 0; i < 20; ++i) srcA += __int_as_float(rm_m[i][lane]);
        float dsum = 0.f;
        #pragma unroll
        for (int j = 0; j < 20; ++j)
            if ((cmbits >> j) & 1u) dsum += __int_as_float(cd_s[j][lane]);
        const float mxv = __int_as_float(mx_s[lane]);

        float vals[7];
        vals[0] = srcA * vw;                          // src-loss min-sum
        vals[1] = (cmbits == 0u) ? 20.f * vw : 0.f;   // rows needing +max_d
        vals[2] = dsum * vw;                          // dst-loss numerator
        vals[3] = vw * (float)__popc(cmbits);         // dst-loss denominator
        const float diff = pn - gn;
        const float ad = fabsf(diff);
        vals[4] = ((ad < 1.f) ? 0.5f * diff * diff : (ad - 0.5f)) * vw;
        vals[5] = vw;                                 // wsum
        vals[6] = (vw > 0.f) ? mxv : 0.f;             // masked max

        #pragma unroll
        for (int o = 32; o > 0; o >>= 1) {
            #pragma unroll
            for (int x = 0; x < 6; ++x) vals[x] += __shfl_down(vals[x], o);
            vals[6] = fmaxf(vals[6], __shfl_down(vals[6], o));
        }
        if (lane == 0) {
            float* rec = ws + (size_t)blockIdx.x * 8;
            #pragma unroll
            for (int x = 0; x < 7; ++x) rec[x] = vals[x];
            __threadfence();   // release record before signaling
            // 16 counters spaced 64B apart; blockIdx&15 -> 64 increments each
            atomicAdd((unsigned*)(ws + 8192) + (blockIdx.x & (NCTR - 1)) * 16, 1u);
        }

        // ---- block 0: spin until all 1024 records signaled, then final reduce
        if (blockIdx.x == 0) {
            volatile unsigned* ctr = (volatile unsigned*)(ws + 8192) + (lane & 15) * 16;
            const unsigned quota = NTILES / NCTR;   // 64 per counter
            for (;;) {
                const bool done = (lane < NCTR) ? (*ctr >= quota) : true;
                if (__all(done)) break;
                __builtin_amdgcn_s_sleep(8);
            }
            __threadfence();   // acquire all records
            float a[6] = {0.f, 0.f, 0.f, 0.f, 0.f, 0.f};
            float fmx = 0.f;
            for (int r = lane; r < NTILES; r += 64) {
                const float* rec = ws + (size_t)r * 8;
                #pragma unroll
                for (int v = 0; v < 6; ++v) a[v] += rec[v];
                fmx = fmaxf(fmx, rec[6]);
            }
            #pragma unroll
            for (int o = 32; o > 0; o >>= 1) {
                #pragma unroll
                for (int v = 0; v < 6; ++v) a[v] += __shfl_down(a[v], o);
                fmx = fmaxf(fmx, __shfl_down(fmx, o));
            }
            if (lane == 0) {
                const float loss_s = (a[0] + a[1] * fmx) / (a[5] * 20.f);
                const float loss_d = a[2] / a[3];
                const float numl   = a[4] / a[5];
                out[0] = loss_s + loss_d + 0.1f * numl;
            }
        }
    }
}

extern "C" void kernel_launch(void* const* d_in, const int* in_sizes, int n_in,
                              void* d_out, int out_size, void* d_ws, size_t ws_size,
                              hipStream_t stream)
{
    const float* pred  = (const float*)d_in[0];
    const float* gt    = (const float*)d_in[1];
    const float* cmask = (const float*)d_in[2];
    const float* vmask = (const float*)d_in[3];
    const float* pnum  = (const float*)d_in[4];
    const float* gnum  = (const float*)d_in[5];
    float* out = (float*)d_out;
    float* ws  = (float*)d_ws;

    // zero the 16 completion counters (1 KB at float-offset 8192)
    hipMemsetAsync(ws + 8192, 0, NCTR * 16 * sizeof(unsigned), stream);
    chamfer_all<<<NTILES, 512, 0, stream>>>(pred, gt, cmask, vmask, pnum, gnum, ws, out);
}